// Round 3
// baseline (281.773 us; speedup 1.0000x reference)
//
#include <hip/hip_runtime.h>
#include <cstdint>
#include <cstddef>

#define AS1 __attribute__((address_space(1)))
#define AS3 __attribute__((address_space(3)))

typedef __bf16 bf16x8 __attribute__((ext_vector_type(8)));
typedef float  f32x4  __attribute__((ext_vector_type(4)));

#define MDIM 16384   // B*S
#define NDIM 1024    // EMBED
#define KDIM 4096    // FFN
#define NQ   8

// ---------------- W2 fp32 -> bf16 (8 elems/thread) ----------------
__global__ __launch_bounds__(256) void conv_w2_kernel(const float* __restrict__ W2,
                                                      __bf16* __restrict__ W2b) {
    size_t base = ((size_t)blockIdx.x * 256 + threadIdx.x) * 8;
    float4 a = *(const float4*)(W2 + base);
    float4 b = *(const float4*)(W2 + base + 4);
    bf16x8 v;
    v[0] = (__bf16)a.x; v[1] = (__bf16)a.y; v[2] = (__bf16)a.z; v[3] = (__bf16)a.w;
    v[4] = (__bf16)b.x; v[5] = (__bf16)b.y; v[6] = (__bf16)b.z; v[7] = (__bf16)b.w;
    *(bf16x8*)(W2b + base) = v;
}

// ------- H = relu( (cos(x[:, :8]) * cos(theta)) @ W1^T + b1 )  -> bf16 -------
#define QROWS 32
__global__ __launch_bounds__(256) void qh_kernel(const float* __restrict__ x,
                                                 const float* __restrict__ theta,
                                                 const float* __restrict__ W1,
                                                 const float* __restrict__ b1,
                                                 __bf16* __restrict__ H) {
    __shared__ __align__(16) float qs[QROWS][NQ];
    const int t  = threadIdx.x;
    const int r0 = blockIdx.x * QROWS;

    {
        const int qr = t >> 3, qi = t & 7;
        const float xv = x[(size_t)(r0 + qr) * 1024 + qi];
        qs[qr][qi] = __cosf(xv) * __cosf(theta[qi]);
    }
    __syncthreads();

#pragma unroll
    for (int fc = 0; fc < 2; ++fc) {
        const int f0 = fc * 2048 + t * 8;
        float w[8][8];
#pragma unroll
        for (int fr = 0; fr < 8; ++fr) {
            float4 a = *(const float4*)(W1 + (size_t)(f0 + fr) * NQ);
            float4 b = *(const float4*)(W1 + (size_t)(f0 + fr) * NQ + 4);
            w[fr][0] = a.x; w[fr][1] = a.y; w[fr][2] = a.z; w[fr][3] = a.w;
            w[fr][4] = b.x; w[fr][5] = b.y; w[fr][6] = b.z; w[fr][7] = b.w;
        }
        float bias[8];
        {
            float4 a = *(const float4*)(b1 + f0);
            float4 b = *(const float4*)(b1 + f0 + 4);
            bias[0] = a.x; bias[1] = a.y; bias[2] = a.z; bias[3] = a.w;
            bias[4] = b.x; bias[5] = b.y; bias[6] = b.z; bias[7] = b.w;
        }
#pragma unroll 1
        for (int r = 0; r < QROWS; ++r) {
            const float4 qa = *(const float4*)&qs[r][0];   // LDS broadcast
            const float4 qb = *(const float4*)&qs[r][4];
            float q[8] = { qa.x, qa.y, qa.z, qa.w, qb.x, qb.y, qb.z, qb.w };
            bf16x8 o;
#pragma unroll
            for (int fr = 0; fr < 8; ++fr) {
                float a = bias[fr];
#pragma unroll
                for (int i = 0; i < 8; ++i) a += q[i] * w[fr][i];
                o[fr] = (__bf16)fmaxf(a, 0.f);
            }
            *(bf16x8*)(H + (size_t)(r0 + r) * KDIM + f0) = o;
        }
    }
}

// ---------------- C[M,N] = A[M,K] * B[N,K]^T + bias, bf16 MFMA ----------------
// 256x256 4-phase schedule (T3+T4 counted vmcnt, T5 setprio):
//  - 512 threads = 8 waves as 2(M) x 4(N); per-wave output 128x64 = acc[8][4].
//  - LDS 128 KiB: 2 buffers x 4 slices {A-k0, A-k1, B-k0, B-k1}, slice =
//    256 rows x 32 cols bf16 (16 KiB) of one BK=64 K-tile.
//  - Slice LDS layout is BLOCK-COLUMN-MAJOR in 16B units (round-2 fix):
//    lambda(row, u) = (row>>3)*32 + u*8 + (row&7),  u = 0..3.
//    A fragment-read 8-lane group (8 consecutive rows, fixed u) then covers
//    lambda&7 = 0..7 -> 8 distinct 16B slots -> all 32 banks once -> ZERO
//    bank conflicts. (Round-2's row-major [256][32] + 2-bit XOR had a 64 B
//    row stride spanning only 16 banks -> 4-way conflicts, 1.7e7 cycles.)
//    global_load_lds writes linearly, so the permutation is applied on the
//    SOURCE side: lane l sources global (row = w*16+(l>>5)*8+(l&7),
//    unit = (l>>3)&3) -- verified bijective vs lambda.
//  - Per K-tile, 4 phases (KS, MG): 8 ds_read_b128 + stage one slice of tile
//    t+1 (2 x global_load_lds w16) + raw s_barrier + lgkmcnt(0) +
//    setprio(1) + 16 MFMA + setprio(0) [+ vmcnt(4)] + raw s_barrier.
//  - vmcnt(4) only at end of phases 1 and 3 (never 0 in main loop); k-slices
//    are staged 3-4 phases before first consumption, 2 slices in flight.
//  - Grid 64x4 = 256 blocks = 1/CU exactly. XCD-affine: xcd=id&7, bn=(id>>3)&3,
//    bm=xcd*8+(id>>5): one bm-strip's 4 bn-blocks stay on one XCD for L2 reuse.
#define BM 256
#define BN 256
#define BK 64
#define SLICE 8192   // elems in one 256-row x 32-col bf16 k-slice (16 KiB)

__device__ __forceinline__ void stage_slice(const __bf16* gsrc, __bf16* ldst) {
    // call 1: LDS units [w*64, +64) = rows w*16..w*16+15; call 2: +512 units
    // = rows +128. Wave writes 64 lanes x 16 B contiguously at uniform base.
    __builtin_amdgcn_global_load_lds((AS1 void*)gsrc, (AS3 void*)ldst, 16, 0, 0);
    __builtin_amdgcn_global_load_lds((AS1 void*)(gsrc + (size_t)128 * KDIM),
                                     (AS3 void*)(ldst + 4096), 16, 0, 0);
}

template<int KS, int MG, bool VM>
__device__ __forceinline__ void phase(const __bf16* bufR, f32x4 (&acc)[8][4],
                                      int axo, int bxo,
                                      const __bf16* gsrc, __bf16* ldst) {
    const __bf16* As = bufR + KS * SLICE;         // A k-slice of current tile
    const __bf16* Bs = bufR + (2 + KS) * SLICE;   // B k-slice
    bf16x8 af[4], bfr[4];
#pragma unroll
    for (int i = 0; i < 4; ++i)                   // +16 rows = +2 blocks = 512
        af[i] = *(const bf16x8*)(As + axo + MG * 2048 + i * 512);
#pragma unroll
    for (int j = 0; j < 4; ++j)
        bfr[j] = *(const bf16x8*)(Bs + bxo + j * 512);
    stage_slice(gsrc, ldst);                      // prefetch slice of tile t+1
    __builtin_amdgcn_s_barrier();                 // raw barrier: no vmcnt drain
    asm volatile("s_waitcnt lgkmcnt(0)" ::: "memory");
    __builtin_amdgcn_sched_barrier(0);            // rule 18: pin MFMA below wait
    __builtin_amdgcn_s_setprio(1);
#pragma unroll
    for (int i = 0; i < 4; ++i)
#pragma unroll
        for (int j = 0; j < 4; ++j)
            acc[MG * 4 + i][j] = __builtin_amdgcn_mfma_f32_16x16x32_bf16(
                af[i], bfr[j], acc[MG * 4 + i][j], 0, 0, 0);
    __builtin_amdgcn_s_setprio(0);
    if constexpr (VM)                             // counted: 2 slices in flight
        asm volatile("s_waitcnt vmcnt(4)" ::: "memory");
    __builtin_amdgcn_s_barrier();
}

__global__ __launch_bounds__(512, 2) void gemm_bt_kernel(const __bf16* __restrict__ A,
                                                         const __bf16* __restrict__ B,
                                                         const float* __restrict__ bias,
                                                         float* __restrict__ C) {
    __shared__ __align__(16) __bf16 lds[2 * 4 * SLICE];   // 128 KiB

    const int tid = threadIdx.x;
    const int w   = tid >> 6;
    const int l   = tid & 63;
    const int id  = blockIdx.x;
    const int xcd = id & 7;
    const int s   = id >> 3;
    const int bn  = s & 3;
    const int bm  = xcd * 8 + (s >> 2);

    const int wm = w >> 2;       // 0..1  (row half)
    const int wn = w & 3;        // 0..3  (col quarter)

    // ---- staging addressing (source-side permutation for lambda layout):
    // LDS unit p = w*64 + l  ->  row = w*16 + (l>>5)*8 + (l&7), u = (l>>3)&3
    const int srow = w * 16 + ((l >> 5) << 3) + (l & 7);
    const int su   = (l >> 3) & 3;
    const __bf16* gA0 = A + (size_t)(bm * BM + srow) * KDIM + su * 8;
    const __bf16* gB0 = B + (size_t)(bn * BN + srow) * KDIM + su * 8;
    const int w512 = w * 512;                // wave's elem offset in a slice

    // ---- fragment read offsets (elems): lambda(row,kq) = (row>>3)*256
    //      + kq*64 + (row&7)*8 with row = base + ml, base % 16 == 0.
    const int ml  = l & 15;
    const int kq  = l >> 4;
    const int lo  = ((ml >> 3) << 8) + ((ml & 7) << 3) + (kq << 6);
    const int axo = wm * 4096 + lo;          // wm*128 rows = 16 blocks
    const int bxo = wn * 2048 + lo;          // wn*64 rows  =  8 blocks

    f32x4 acc[8][4] = {};

    // ---- prologue: stage all 4 slices of tile 0 into buf0, wait k0 ready
    stage_slice(gA0,      lds + 0 * SLICE + w512);   // A k0
    stage_slice(gB0,      lds + 2 * SLICE + w512);   // B k0
    stage_slice(gA0 + 32, lds + 1 * SLICE + w512);   // A k1
    stage_slice(gB0 + 32, lds + 3 * SLICE + w512);   // B k1
    asm volatile("s_waitcnt vmcnt(4)" ::: "memory"); // k0 slices complete
    __builtin_amdgcn_s_barrier();

#pragma unroll 1
    for (int t = 0; t < KDIM / BK; ++t) {
        const __bf16* bufR = lds + (t & 1) * (4 * SLICE);
        __bf16* bufW = lds + ((t + 1) & 1) * (4 * SLICE);
        // staged tile's K base (clamped at the end: harmless re-stage of t=63)
        const int tn = (t < KDIM / BK - 1) ? (t + 1) * BK : (KDIM / BK - 1) * BK;

        phase<0, 0, false>(bufR, acc, axo, bxo, gA0 + tn,      bufW + 0 * SLICE + w512);
        phase<0, 1, true >(bufR, acc, axo, bxo, gB0 + tn,      bufW + 2 * SLICE + w512);
        phase<1, 0, false>(bufR, acc, axo, bxo, gA0 + tn + 32, bufW + 1 * SLICE + w512);
        phase<1, 1, true >(bufR, acc, axo, bxo, gB0 + tn + 32, bufW + 3 * SLICE + w512);
    }

    // ---- epilogue: 16x16 C/D layout col=lane&15, row=(lane>>4)*4+reg
    const int cm0 = bm * BM + wm * 128;
    const int cn0 = bn * BN + wn * 64;
#pragma unroll
    for (int j = 0; j < 4; ++j) {
        const int col = cn0 + j * 16 + ml;
        const float bv = bias[col];
#pragma unroll
        for (int i = 0; i < 8; ++i) {
            const int row0 = cm0 + i * 16 + kq * 4;
#pragma unroll
            for (int r = 0; r < 4; ++r)
                C[(size_t)(row0 + r) * NDIM + col] = acc[i][j][r] + bv;
        }
    }
}

extern "C" void kernel_launch(void* const* d_in, const int* in_sizes, int n_in,
                              void* d_out, int out_size, void* d_ws, size_t ws_size,
                              hipStream_t stream) {
    const float* x     = (const float*)d_in[0];
    const float* theta = (const float*)d_in[1];
    const float* W1    = (const float*)d_in[2];
    const float* b1    = (const float*)d_in[3];
    const float* W2    = (const float*)d_in[4];
    const float* b2    = (const float*)d_in[5];
    float* out = (float*)d_out;

    __bf16* H   = (__bf16*)d_ws;                                    // 128 MiB
    __bf16* W2b = (__bf16*)((char*)d_ws + (size_t)MDIM * KDIM * 2); // + 8 MiB

    conv_w2_kernel<<<(KDIM * NDIM) / (256 * 8), 256, 0, stream>>>(W2, W2b);
    qh_kernel<<<MDIM / QROWS, 256, 0, stream>>>(x, theta, W1, b1, H);
    gemm_bt_kernel<<<(MDIM / BM) * (NDIM / BN), 512, 0, stream>>>(H, W2b, b2, out);
}

// Round 4
// 280.180 us; speedup vs baseline: 1.0057x; 1.0057x over previous
//
#include <hip/hip_runtime.h>
#include <cstdint>
#include <cstddef>

#define AS1 __attribute__((address_space(1)))
#define AS3 __attribute__((address_space(3)))

typedef __bf16 bf16x8 __attribute__((ext_vector_type(8)));
typedef float  f32x4  __attribute__((ext_vector_type(4)));
typedef float  f32x16 __attribute__((ext_vector_type(16)));

#define MDIM 16384   // B*S
#define NDIM 1024    // EMBED
#define KDIM 4096    // FFN
#define NQ   8

// ---------------- W2 fp32 -> bf16 (8 elems/thread) ----------------
__global__ __launch_bounds__(256) void conv_w2_kernel(const float* __restrict__ W2,
                                                      __bf16* __restrict__ W2b) {
    size_t base = ((size_t)blockIdx.x * 256 + threadIdx.x) * 8;
    float4 a = *(const float4*)(W2 + base);
    float4 b = *(const float4*)(W2 + base + 4);
    bf16x8 v;
    v[0] = (__bf16)a.x; v[1] = (__bf16)a.y; v[2] = (__bf16)a.z; v[3] = (__bf16)a.w;
    v[4] = (__bf16)b.x; v[5] = (__bf16)b.y; v[6] = (__bf16)b.z; v[7] = (__bf16)b.w;
    *(bf16x8*)(W2b + base) = v;
}

// ------- H = relu( (cos(x[:, :8]) * cos(theta)) @ W1^T + b1 )  -> bf16 -------
#define QROWS 32
__global__ __launch_bounds__(256) void qh_kernel(const float* __restrict__ x,
                                                 const float* __restrict__ theta,
                                                 const float* __restrict__ W1,
                                                 const float* __restrict__ b1,
                                                 __bf16* __restrict__ H) {
    __shared__ __align__(16) float qs[QROWS][NQ];
    const int t  = threadIdx.x;
    const int r0 = blockIdx.x * QROWS;

    {
        const int qr = t >> 3, qi = t & 7;
        const float xv = x[(size_t)(r0 + qr) * 1024 + qi];
        qs[qr][qi] = __cosf(xv) * __cosf(theta[qi]);
    }
    __syncthreads();

#pragma unroll
    for (int fc = 0; fc < 2; ++fc) {
        const int f0 = fc * 2048 + t * 8;
        float w[8][8];
#pragma unroll
        for (int fr = 0; fr < 8; ++fr) {
            float4 a = *(const float4*)(W1 + (size_t)(f0 + fr) * NQ);
            float4 b = *(const float4*)(W1 + (size_t)(f0 + fr) * NQ + 4);
            w[fr][0] = a.x; w[fr][1] = a.y; w[fr][2] = a.z; w[fr][3] = a.w;
            w[fr][4] = b.x; w[fr][5] = b.y; w[fr][6] = b.z; w[fr][7] = b.w;
        }
        float bias[8];
        {
            float4 a = *(const float4*)(b1 + f0);
            float4 b = *(const float4*)(b1 + f0 + 4);
            bias[0] = a.x; bias[1] = a.y; bias[2] = a.z; bias[3] = a.w;
            bias[4] = b.x; bias[5] = b.y; bias[6] = b.z; bias[7] = b.w;
        }
#pragma unroll 1
        for (int r = 0; r < QROWS; ++r) {
            const float4 qa = *(const float4*)&qs[r][0];   // LDS broadcast
            const float4 qb = *(const float4*)&qs[r][4];
            float q[8] = { qa.x, qa.y, qa.z, qa.w, qb.x, qb.y, qb.z, qb.w };
            bf16x8 o;
#pragma unroll
            for (int fr = 0; fr < 8; ++fr) {
                float a = bias[fr];
#pragma unroll
                for (int i = 0; i < 8; ++i) a += q[i] * w[fr][i];
                o[fr] = (__bf16)fmaxf(a, 0.f);
            }
            *(bf16x8*)(H + (size_t)(r0 + r) * KDIM + f0) = o;
        }
    }
}

// ---------------- C[M,N] = A[M,K] * B[N,K]^T + bias, bf16 MFMA ----------------
// Round-4: 32x32x16 MFMA (2x FLOP per 16B operand -> halves LDS-read traffic
// per FLOP; round-3 counters showed LDS pipe ~2560 cyc/K-tile co-equal with
// MFMA 2483 in lockstep phases). 2 phases per K-tile (was 4): each phase =
// 12 ds_read_b128 + stage 2 slices (4 gload) + barrier + lgkmcnt(0) +
// setprio(1) + 16 x mfma_32x32x16 + setprio(0) + vmcnt(4) + barrier.
//  - 512 threads = 8 waves as 2(M) x 4(N); per-wave output 128x64 =
//    4x2 tiles of 32x32, acc = f32x16[4][2].
//  - LDS 128 KiB: 2 buffers x 4 slices {A-k0, A-k1, B-k0, B-k1}, slice =
//    256 rows x 32 cols bf16 (16 KiB), BK=64.
//  - Slice layout block-column-major in 16B units (round-3, measured 0
//    conflicts): lambda(row, u) = (row>>3)*32 + u*8 + (row&7). 32-row
//    fragment groups hit 64 distinct units, each bank exactly 8x -> clean.
//    Source-side permutation on global addr (global_load_lds writes linear).
//  - vmcnt(4) at each phase end retires exactly the slice pair the NEXT
//    phase reads (4-load/phase FIFO); prefetch distance = 2 phases ~ 2000 cyc
//    > 900 cyc HBM latency.
//  - Grid 64x4 = 256 blocks = 1/CU. XCD-affine: xcd=id&7, bn=(id>>3)&3,
//    bm=xcd*8+(id>>5).
#define BM 256
#define BN 256
#define BK 64
#define SLICE 8192   // elems in one 256-row x 32-col bf16 k-slice (16 KiB)

__device__ __forceinline__ void stage_slice(const __bf16* gsrc, __bf16* ldst) {
    __builtin_amdgcn_global_load_lds((AS1 void*)gsrc, (AS3 void*)ldst, 16, 0, 0);
    __builtin_amdgcn_global_load_lds((AS1 void*)(gsrc + (size_t)128 * KDIM),
                                     (AS3 void*)(ldst + 4096), 16, 0, 0);
}

template<int KS>
__device__ __forceinline__ void phase(const __bf16* bufR, f32x16 (&acc)[4][2],
                                      int axo, int bxo,
                                      const __bf16* gsrcA, __bf16* ldstA,
                                      const __bf16* gsrcB, __bf16* ldstB) {
    const __bf16* As = bufR + KS * SLICE;         // A k-slice of current tile
    const __bf16* Bs = bufR + (2 + KS) * SLICE;   // B k-slice
    bf16x8 af[4][2], bf[2][2];
#pragma unroll
    for (int i = 0; i < 4; ++i)                   // i*32 rows = i*1024 elems
#pragma unroll
        for (int s = 0; s < 2; ++s)               // k-step: unit +s*2 = +128
            af[i][s] = *(const bf16x8*)(As + axo + i * 1024 + s * 128);
#pragma unroll
    for (int j = 0; j < 2; ++j)
#pragma unroll
        for (int s = 0; s < 2; ++s)
            bf[j][s] = *(const bf16x8*)(Bs + bxo + j * 1024 + s * 128);
    stage_slice(gsrcA, ldstA);                    // prefetch 2 slices of t+1
    stage_slice(gsrcB, ldstB);
    __builtin_amdgcn_s_barrier();                 // raw barrier: no vmcnt drain
    asm volatile("s_waitcnt lgkmcnt(0)" ::: "memory");
    __builtin_amdgcn_sched_barrier(0);            // rule 18: pin MFMA below wait
    __builtin_amdgcn_s_setprio(1);
#pragma unroll
    for (int s = 0; s < 2; ++s)
#pragma unroll
        for (int i = 0; i < 4; ++i)
#pragma unroll
            for (int j = 0; j < 2; ++j)
                acc[i][j] = __builtin_amdgcn_mfma_f32_32x32x16_bf16(
                    af[i][s], bf[j][s], acc[i][j], 0, 0, 0);
    __builtin_amdgcn_s_setprio(0);
    asm volatile("s_waitcnt vmcnt(4)" ::: "memory");  // retire next phase's pair
    __builtin_amdgcn_s_barrier();
}

__global__ __launch_bounds__(512, 2) void gemm_bt_kernel(const __bf16* __restrict__ A,
                                                         const __bf16* __restrict__ B,
                                                         const float* __restrict__ bias,
                                                         float* __restrict__ C) {
    __shared__ __align__(16) __bf16 lds[2 * 4 * SLICE];   // 128 KiB

    const int tid = threadIdx.x;
    const int w   = tid >> 6;
    const int l   = tid & 63;
    const int id  = blockIdx.x;
    const int xcd = id & 7;
    const int s   = id >> 3;
    const int bn  = s & 3;
    const int bm  = xcd * 8 + (s >> 2);

    const int wm = w >> 2;       // 0..1  (row half)
    const int wn = w & 3;        // 0..3  (col quarter)

    // ---- staging addressing (source-side permutation for lambda layout):
    // LDS unit p = w*64 + l  ->  row = w*16 + (l>>5)*8 + (l&7), u = (l>>3)&3
    const int srow = w * 16 + ((l >> 5) << 3) + (l & 7);
    const int su   = (l >> 3) & 3;
    const __bf16* gA0 = A + (size_t)(bm * BM + srow) * KDIM + su * 8;
    const __bf16* gB0 = B + (size_t)(bn * BN + srow) * KDIM + su * 8;
    const int w512 = w * 512;                // wave's elem offset in a slice

    // ---- fragment read offsets (elems): lambda gives, for row = base + ml
    // (base%32==0): addr = base*32 + (ml>>3)*256 + (ml&7)*8 + unit*64.
    const int ml  = l & 31;
    const int kh  = l >> 5;                  // k-half of the 16-k-step
    const int lo  = ((ml >> 3) << 8) + ((ml & 7) << 3) + (kh << 6);
    const int axo = wm * 4096 + lo;          // wm*128 rows
    const int bxo = wn * 2048 + lo;          // wn*64 rows

    f32x16 acc[4][2] = {};

    // ---- prologue: stage all 4 slices of tile 0 into buf0, wait k0 ready
    stage_slice(gA0,      lds + 0 * SLICE + w512);   // A k0
    stage_slice(gB0,      lds + 2 * SLICE + w512);   // B k0
    stage_slice(gA0 + 32, lds + 1 * SLICE + w512);   // A k1
    stage_slice(gB0 + 32, lds + 3 * SLICE + w512);   // B k1
    asm volatile("s_waitcnt vmcnt(4)" ::: "memory"); // k0 slices complete
    __builtin_amdgcn_s_barrier();

#pragma unroll 1
    for (int t = 0; t < KDIM / BK; ++t) {
        const __bf16* bufR = lds + (t & 1) * (4 * SLICE);
        __bf16* bufW = lds + ((t + 1) & 1) * (4 * SLICE);
        // staged tile's K base (clamped at the end: harmless re-stage of t=63)
        const int tn = (t < KDIM / BK - 1) ? (t + 1) * BK : (KDIM / BK - 1) * BK;

        phase<0>(bufR, acc, axo, bxo,
                 gA0 + tn,      bufW + 0 * SLICE + w512,
                 gB0 + tn,      bufW + 2 * SLICE + w512);
        phase<1>(bufR, acc, axo, bxo,
                 gA0 + tn + 32, bufW + 1 * SLICE + w512,
                 gB0 + tn + 32, bufW + 3 * SLICE + w512);
    }

    // ---- epilogue: 32x32 C/D layout col=lane&31, row=(reg&3)+8*(reg>>2)+4*kh
    const int cm0 = bm * BM + wm * 128;
    const int cn0 = bn * BN + wn * 64;
#pragma unroll
    for (int j = 0; j < 2; ++j) {
        const int col = cn0 + j * 32 + ml;
        const float bv = bias[col];
#pragma unroll
        for (int i = 0; i < 4; ++i) {
            const int rowbase = cm0 + i * 32 + kh * 4;
#pragma unroll
            for (int reg = 0; reg < 16; ++reg) {
                const int row = rowbase + (reg & 3) + ((reg >> 2) << 3);
                C[(size_t)row * NDIM + col] = acc[i][j][reg] + bv;
            }
        }
    }
}

extern "C" void kernel_launch(void* const* d_in, const int* in_sizes, int n_in,
                              void* d_out, int out_size, void* d_ws, size_t ws_size,
                              hipStream_t stream) {
    const float* x     = (const float*)d_in[0];
    const float* theta = (const float*)d_in[1];
    const float* W1    = (const float*)d_in[2];
    const float* b1    = (const float*)d_in[3];
    const float* W2    = (const float*)d_in[4];
    const float* b2    = (const float*)d_in[5];
    float* out = (float*)d_out;

    __bf16* H   = (__bf16*)d_ws;                                    // 128 MiB
    __bf16* W2b = (__bf16*)((char*)d_ws + (size_t)MDIM * KDIM * 2); // + 8 MiB

    conv_w2_kernel<<<(KDIM * NDIM) / (256 * 8), 256, 0, stream>>>(W2, W2b);
    qh_kernel<<<MDIM / QROWS, 256, 0, stream>>>(x, theta, W1, b1, H);
    gemm_bt_kernel<<<(MDIM / BM) * (NDIM / BN), 512, 0, stream>>>(H, W2b, b2, out);
}